// Round 1
// baseline (1080.838 us; speedup 1.0000x reference)
//
#include <hip/hip_runtime.h>
#include <hip/hip_bf16.h>

// GEMM: out[256,1000] = X[256,150528] * C[1000,150528]^T  (fp32 in/out)
// Strategy: split-D (split-K) bf16 MFMA GEMM, 128x128 tiles, 4 waves/block,
// on-the-fly fp32->bf16 conversion through LDS, atomicAdd partial reduction.

#define BM 128
#define BN 128
#define BK 32
#define LDSS 40               // 32 + 8 pad (bf16 units); row = 80 B, 16B-aligned
#define SPLIT 32
#define NCLS 1000
#define MROWS 256
#define DIM 150528
#define DCHUNK (DIM / SPLIT)  // 4704
#define KITERS (DCHUNK / BK)  // 147 exact

typedef short bf16x8 __attribute__((ext_vector_type(8)));
typedef float f32x4 __attribute__((ext_vector_type(4)));

static __device__ __forceinline__ unsigned short f2bf(float f) {
    union { __hip_bfloat16 h; unsigned short u; } cv;
    cv.h = __float2bfloat16(f);
    return cv.u;
}

__global__ __launch_bounds__(256) void classifier_gemm(
    const float* __restrict__ X, const float* __restrict__ W,
    float* __restrict__ out)
{
    __shared__ unsigned short As[BM * LDSS];
    __shared__ unsigned short Bs[BN * LDSS];

    const int t    = threadIdx.x;
    const int lane = t & 63;
    const int wave = t >> 6;
    const int wm   = wave >> 1;   // 0..1 (M half)
    const int wn   = wave & 1;    // 0..1 (N half)

    const int bi = blockIdx.x & 1;    // M block: 0..1
    const int bj = blockIdx.x >> 1;   // N block: 0..7
    const int s  = blockIdx.y;        // D chunk: 0..31

    const int row0 = bi * BM;
    const int col0 = bj * BN;
    const size_t d0 = (size_t)s * DCHUNK;

    // ---- staging assignment: thread t loads row (t>>1), 16 floats at (t&1)*16
    const int ar = t >> 1;            // 0..127
    const int ac = (t & 1) * 16;      // 0 or 16
    const float* aptr = X + (size_t)(row0 + ar) * DIM + d0 + ac;
    const int brow = col0 + ar;
    const bool bok = brow < NCLS;
    const float* bptr = W + (size_t)(bok ? brow : 0) * DIM + d0 + ac;

    f32x4 acc[4][4];
    #pragma unroll
    for (int i = 0; i < 4; ++i)
        #pragma unroll
        for (int j = 0; j < 4; ++j)
            acc[i][j] = (f32x4){0.f, 0.f, 0.f, 0.f};

    // register prefetch buffers (iteration 0)
    float4 av[4], bv[4];
    #pragma unroll
    for (int q = 0; q < 4; ++q) {
        av[q] = *(const float4*)(aptr + q * 4);
        bv[q] = bok ? *(const float4*)(bptr + q * 4) : make_float4(0.f, 0.f, 0.f, 0.f);
    }
    aptr += BK; bptr += BK;

    // LDS offsets (bf16/ushort units)
    const int a_off = (wm * 64 + (lane & 15)) * LDSS + (lane >> 4) * 8;
    const int b_off = (wn * 64 + (lane & 15)) * LDSS + (lane >> 4) * 8;
    const int w_off = ar * LDSS + ac;

    for (int it = 0; it < KITERS; ++it) {
        // convert current registers to bf16, write to LDS
        #pragma unroll
        for (int q = 0; q < 4; ++q) {
            ushort4 ap, bp;
            ap.x = f2bf(av[q].x); ap.y = f2bf(av[q].y);
            ap.z = f2bf(av[q].z); ap.w = f2bf(av[q].w);
            bp.x = f2bf(bv[q].x); bp.y = f2bf(bv[q].y);
            bp.z = f2bf(bv[q].z); bp.w = f2bf(bv[q].w);
            *(ushort4*)&As[w_off + q * 4] = ap;
            *(ushort4*)&Bs[w_off + q * 4] = bp;
        }
        // issue next iteration's global loads (latency hides under MFMA phase)
        if (it + 1 < KITERS) {
            #pragma unroll
            for (int q = 0; q < 4; ++q) {
                av[q] = *(const float4*)(aptr + q * 4);
                bv[q] = bok ? *(const float4*)(bptr + q * 4) : make_float4(0.f, 0.f, 0.f, 0.f);
            }
            aptr += BK; bptr += BK;
        }
        __syncthreads();

        bf16x8 afr[4], bfr[4];
        #pragma unroll
        for (int mt = 0; mt < 4; ++mt)
            afr[mt] = *(const bf16x8*)&As[a_off + mt * 16 * LDSS];
        #pragma unroll
        for (int nt = 0; nt < 4; ++nt)
            bfr[nt] = *(const bf16x8*)&Bs[b_off + nt * 16 * LDSS];

        #pragma unroll
        for (int mt = 0; mt < 4; ++mt)
            #pragma unroll
            for (int nt = 0; nt < 4; ++nt)
                acc[mt][nt] = __builtin_amdgcn_mfma_f32_16x16x32_bf16(
                    afr[mt], bfr[nt], acc[mt][nt], 0, 0, 0);

        __syncthreads();
    }

    // ---- epilogue: atomic-add the partial 128x128 tile into out
    // C/D layout: col = lane&15, row = (lane>>4)*4 + reg   [m89/m91 verified]
    const int orow0 = row0 + wm * 64 + (lane >> 4) * 4;
    const int ocol0 = col0 + wn * 64 + (lane & 15);
    #pragma unroll
    for (int mt = 0; mt < 4; ++mt) {
        #pragma unroll
        for (int nt = 0; nt < 4; ++nt) {
            const int ocol = ocol0 + nt * 16;
            if (ocol < NCLS) {
                #pragma unroll
                for (int e = 0; e < 4; ++e) {
                    const int orow = orow0 + mt * 16 + e;
                    atomicAdd(out + (size_t)orow * NCLS + ocol, acc[mt][nt][e]);
                }
            }
        }
    }
}

extern "C" void kernel_launch(void* const* d_in, const int* in_sizes, int n_in,
                              void* d_out, int out_size, void* d_ws, size_t ws_size,
                              hipStream_t stream) {
    const float* X = (const float*)d_in[0];   // [256, 150528]
    const float* W = (const float*)d_in[1];   // [1000, 150528]
    float* out = (float*)d_out;               // [256, 1000]

    // zero the output (harness poisons it to 0xAA before every launch)
    hipMemsetAsync(out, 0, (size_t)out_size * sizeof(float), stream);

    dim3 grid(16, SPLIT);   // x: (bi 0..1, bj 0..7), y: D chunk
    dim3 block(256);
    classifier_gemm<<<grid, block, 0, stream>>>(X, W, out);
}

// Round 2
// 1000.025 us; speedup vs baseline: 1.0808x; 1.0808x over previous
//
#include <hip/hip_runtime.h>
#include <hip/hip_bf16.h>

// GEMM: out[256,1000] = X[256,150528] * C[1000,150528]^T  (fp32 in/out)
// Split-K bf16 MFMA GEMM, 128x128 tiles, 4 waves/block, fp32->bf16 via LDS,
// atomicAdd partial reduction.
// R2: coalesced staging (8 lanes per 128B row-segment), SPLIT=96 for occupancy.

#define BM 128
#define BN 128
#define BK 32
#define LDSS 40               // 32 + 8 pad (bf16 units); row = 80 B
#define SPLIT 96
#define NCLS 1000
#define DIM 150528
#define DCHUNK (DIM / SPLIT)  // 1568
#define KITERS (DCHUNK / BK)  // 49 exact

typedef short bf16x8 __attribute__((ext_vector_type(8)));
typedef float f32x4 __attribute__((ext_vector_type(4)));

static __device__ __forceinline__ unsigned short f2bf(float f) {
    union { __hip_bfloat16 h; unsigned short u; } cv;
    cv.h = __float2bfloat16(f);
    return cv.u;
}

__global__ __launch_bounds__(256) void classifier_gemm(
    const float* __restrict__ X, const float* __restrict__ W,
    float* __restrict__ out)
{
    __shared__ unsigned short As[BM * LDSS];
    __shared__ unsigned short Bs[BN * LDSS];

    const int t    = threadIdx.x;
    const int lane = t & 63;
    const int wave = t >> 6;
    const int wm   = wave >> 1;   // 0..1 (M half)
    const int wn   = wave & 1;    // 0..1 (N half)

    const int bi = blockIdx.x & 1;    // M block: 0..1
    const int bj = blockIdx.x >> 1;   // N block: 0..7
    const int s  = blockIdx.y;        // D chunk: 0..95

    const int row0 = bi * BM;
    const int col0 = bj * BN;
    const size_t d0 = (size_t)s * DCHUNK;

    // ---- coalesced staging map: chunk f = k*256 + t covers
    //      row = f>>3 (0..127), col = (f&7)*4 floats (16 B).
    //      Consecutive lanes -> consecutive 16B chunks of the same row:
    //      one dwordx4 inst = 8 rows x 128 B fully-consumed lines.
    const int frow = t >> 3;          // 0..31 (+32 per k)
    const int fcol = (t & 7) * 4;     // float offset within BK row segment

    const float* aptr = X + (size_t)(row0 + frow) * DIM + d0 + fcol;
    const float* bbase = W + d0 + fcol;
    int  brows[4];
    bool bok[4];
    #pragma unroll
    for (int k = 0; k < 4; ++k) {
        const int br = col0 + 32 * k + frow;
        bok[k]   = br < NCLS;
        brows[k] = bok[k] ? br : 0;
    }

    f32x4 acc[4][4];
    #pragma unroll
    for (int i = 0; i < 4; ++i)
        #pragma unroll
        for (int j = 0; j < 4; ++j)
            acc[i][j] = (f32x4){0.f, 0.f, 0.f, 0.f};

    // register prefetch (iteration 0)
    float4 av[4], bv[4];
    #pragma unroll
    for (int k = 0; k < 4; ++k) {
        av[k] = *(const float4*)(aptr + (size_t)(32 * k) * DIM);
        bv[k] = bok[k] ? *(const float4*)(bbase + (size_t)brows[k] * DIM)
                       : make_float4(0.f, 0.f, 0.f, 0.f);
    }
    size_t koff = BK;   // float offset into the chunk for the next prefetch

    // LDS offsets (ushort units)
    const int a_off = (wm * 64 + (lane & 15)) * LDSS + (lane >> 4) * 8;
    const int b_off = (wn * 64 + (lane & 15)) * LDSS + (lane >> 4) * 8;
    const int w_off0 = frow * LDSS + (t & 7) * 4;

    for (int it = 0; it < KITERS; ++it) {
        // convert current registers to bf16, write to LDS
        #pragma unroll
        for (int k = 0; k < 4; ++k) {
            ushort4 ap, bp;
            ap.x = f2bf(av[k].x); ap.y = f2bf(av[k].y);
            ap.z = f2bf(av[k].z); ap.w = f2bf(av[k].w);
            bp.x = f2bf(bv[k].x); bp.y = f2bf(bv[k].y);
            bp.z = f2bf(bv[k].z); bp.w = f2bf(bv[k].w);
            *(ushort4*)&As[w_off0 + 32 * k * LDSS] = ap;
            *(ushort4*)&Bs[w_off0 + 32 * k * LDSS] = bp;
        }
        // prefetch next iteration (latency hides under MFMA + other waves)
        if (it + 1 < KITERS) {
            #pragma unroll
            for (int k = 0; k < 4; ++k) {
                av[k] = *(const float4*)(aptr + (size_t)(32 * k) * DIM + koff);
                bv[k] = bok[k]
                    ? *(const float4*)(bbase + (size_t)brows[k] * DIM + koff)
                    : make_float4(0.f, 0.f, 0.f, 0.f);
            }
            koff += BK;
        }
        __syncthreads();

        bf16x8 afr[4], bfr[4];
        #pragma unroll
        for (int mt = 0; mt < 4; ++mt)
            afr[mt] = *(const bf16x8*)&As[a_off + mt * 16 * LDSS];
        #pragma unroll
        for (int nt = 0; nt < 4; ++nt)
            bfr[nt] = *(const bf16x8*)&Bs[b_off + nt * 16 * LDSS];

        #pragma unroll
        for (int mt = 0; mt < 4; ++mt)
            #pragma unroll
            for (int nt = 0; nt < 4; ++nt)
                acc[mt][nt] = __builtin_amdgcn_mfma_f32_16x16x32_bf16(
                    afr[mt], bfr[nt], acc[mt][nt], 0, 0, 0);

        __syncthreads();
    }

    // ---- epilogue: atomic-add the partial 128x128 tile into out
    // C/D layout: col = lane&15, row = (lane>>4)*4 + reg
    const int orow0 = row0 + wm * 64 + (lane >> 4) * 4;
    const int ocol0 = col0 + wn * 64 + (lane & 15);
    #pragma unroll
    for (int mt = 0; mt < 4; ++mt) {
        #pragma unroll
        for (int nt = 0; nt < 4; ++nt) {
            const int ocol = ocol0 + nt * 16;
            if (ocol < NCLS) {
                #pragma unroll
                for (int e = 0; e < 4; ++e) {
                    const int orow = orow0 + mt * 16 + e;
                    atomicAdd(out + (size_t)orow * NCLS + ocol, acc[mt][nt][e]);
                }
            }
        }
    }
}

extern "C" void kernel_launch(void* const* d_in, const int* in_sizes, int n_in,
                              void* d_out, int out_size, void* d_ws, size_t ws_size,
                              hipStream_t stream) {
    const float* X = (const float*)d_in[0];   // [256, 150528]
    const float* W = (const float*)d_in[1];   // [1000, 150528]
    float* out = (float*)d_out;               // [256, 1000]

    hipMemsetAsync(out, 0, (size_t)out_size * sizeof(float), stream);

    dim3 grid(16, SPLIT);   // x: (bi 0..1, bj 0..7), y: D chunk
    dim3 block(256);
    classifier_gemm<<<grid, block, 0, stream>>>(X, W, out);
}